// Round 4
// baseline (102.752 us; speedup 1.0000x reference)
//
#include <hip/hip_runtime.h>

typedef unsigned short u16;
typedef unsigned int u32;
typedef __attribute__((ext_vector_type(8))) short bf16x8;
typedef __attribute__((ext_vector_type(4))) short bf16x4v;
typedef __attribute__((ext_vector_type(4))) float f32x4;

#define NWAYS 10
#define NC 128
#define NHW 1024

__device__ __forceinline__ u16 f2bf(float f) {
  u32 u = __builtin_bit_cast(u32, f);
  return (u16)((u + 0x7fffu + ((u >> 16) & 1u)) >> 16);  // RNE
}

// ---------------- Kernel 1: per-chunk Gram partials (NO atomics) ----------------
// Gpart[j*20+chunk][c][d] = sum_{n in chunk} s_c s_d ; mpart[j*20+chunk][c] = sum s_c
// grid = 10 classes * 20 chunks of 256 n ; block 256
__global__ __launch_bounds__(256) void k_covg(const float* __restrict__ sup,
                                              float* __restrict__ Gpart,
                                              float* __restrict__ mpart) {
  __shared__ u16 tile[NC * 256];  // swizzled [c][n], 64 KiB
  __shared__ float ssum[NC];
  int j = blockIdx.x / 20, chunk = blockIdx.x % 20;
  int shot = chunk >> 2, p0 = (chunk & 3) * 256;
  int t = threadIdx.x;
  const float* srcbase = sup + ((size_t)(j * 5 + shot) * NC) * NHW + p0;
  // coalesced staging: wave w loads row it*4+w contiguously (64 x float4)
#pragma unroll 8
  for (int it = 0; it < 32; ++it) {
    int c = it * 4 + (t >> 6);
    int pos = t & 63;
    float4 v = *(const float4*)(srcbase + (size_t)c * NHW + pos * 4);
    int nl = pos * 4;
    int idx = c * 256 + (((nl >> 3) ^ (c & 15)) << 3) + (nl & 7);
    bf16x4v h;
    h[0] = (short)f2bf(v.x); h[1] = (short)f2bf(v.y);
    h[2] = (short)f2bf(v.z); h[3] = (short)f2bf(v.w);
    *(bf16x4v*)&tile[idx] = h;
    float s = v.x + v.y + v.z + v.w;
#pragma unroll
    for (int m = 1; m <= 32; m <<= 1) s += __shfl_xor(s, m, 64);
    if ((t & 63) == 0) ssum[c] = s;  // unique writer per row
  }
  __syncthreads();
  if (t < NC) mpart[(size_t)(j * 20 + chunk) * NC + t] = ssum[t];

  int w = t >> 6, l = t & 63, lr = l & 15, lg = l >> 4;
  f32x4 acc[2][8];
#pragma unroll
  for (int a = 0; a < 2; ++a)
#pragma unroll
    for (int bt = 0; bt < 8; ++bt) acc[a][bt] = (f32x4){0.f, 0.f, 0.f, 0.f};
#pragma unroll 1
  for (int kb = 0; kb < 8; ++kb) {
    int nn = kb * 32 + lg * 8;
    bf16x8 frag[8];
#pragma unroll
    for (int ti = 0; ti < 8; ++ti) {
      int cc = ti * 16 + lr;
      frag[ti] = *(const bf16x8*)&tile[cc * 256 + (((nn >> 3) ^ (cc & 15)) << 3)];
    }
    bf16x8 fa[2];
#pragma unroll
    for (int a = 0; a < 2; ++a) {
      int cc = (2 * w + a) * 16 + lr;
      fa[a] = *(const bf16x8*)&tile[cc * 256 + (((nn >> 3) ^ (cc & 15)) << 3)];
    }
#pragma unroll
    for (int a = 0; a < 2; ++a)
#pragma unroll
      for (int bt = 0; bt < 8; ++bt)
        acc[a][bt] = __builtin_amdgcn_mfma_f32_16x16x32_bf16(fa[a], frag[bt], acc[a][bt], 0, 0, 0);
  }
  float* gp = Gpart + ((size_t)(j * 20 + chunk) << 14);
#pragma unroll
  for (int a = 0; a < 2; ++a)
#pragma unroll
    for (int bt = 0; bt < 8; ++bt)
#pragma unroll
      for (int r = 0; r < 4; ++r) {
        int cr = (2 * w + a) * 16 + lg * 4 + r;  // C/D: row=(lane>>4)*4+reg
        int d = bt * 16 + lr;                    //      col=lane&15
        gp[cr * NC + d] = acc[a][bt][r];         // plain store: block owns slab
      }
}

// ---------------- Kernel 2: reduce partials -> fp32 cov ----------------
// grid = 10 j * 16 rowgroups of 8 rows ; block 256
__global__ __launch_bounds__(256) void k_fin(const float* __restrict__ Gpart,
                                             const float* __restrict__ mpart,
                                             float* __restrict__ covf) {
  __shared__ float msd[NC];
  int j = blockIdx.x >> 4, rg = blockIdx.x & 15;
  int t = threadIdx.x;
  if (t < NC) {
    float s = 0.f;
#pragma unroll
    for (int k = 0; k < 20; ++k) s += mpart[(size_t)(j * 20 + k) * NC + t];
    msd[t] = s;
  }
  __syncthreads();
#pragma unroll
  for (int i = 0; i < 4; ++i) {
    int e = i * 256 + t;          // 0..1023 over 8 rows x 128 cols
    int r = e >> 7, d = e & 127;
    int c = rg * 8 + r;
    float g = 0.f;
#pragma unroll
    for (int k = 0; k < 20; ++k) g += Gpart[(((size_t)(j * 20 + k)) << 14) + c * NC + d];
    covf[(((size_t)j) << 14) + c * NC + d] =
        (g - msd[c] * msd[d] * (1.0f / 5120.0f)) * (1.0f / 5119.0f);
  }
}

// ---------------- Kernel 3: weighted q-Gram quarters, no atomics, no pre-zero ----
// Wraw[qr*64+b][c][d] = sum_{p in quarter qr} w_p q_c q_d ; ss[qr*64+b][c] = sum q_c^2
// grid = 64 b * 4 quarters of 256 p ; block 512 (8 waves); 2 chunks of 128 p
__global__ __launch_bounds__(512) void k_wgram(const float* __restrict__ q,
                                               const float* __restrict__ cw,
                                               float* __restrict__ Wraw,
                                               float* __restrict__ ss) {
  __shared__ u16 traw[NC * 128];  // 32 KiB [c][128p] swizzled
  __shared__ u16 twgt[NC * 128];  // 32 KiB, w_p-scaled
  __shared__ float ss_loc[NC];
  int bid = blockIdx.x;
  int b = bid >> 2, qr = bid & 3;
  int t = threadIdx.x;
  int w = t >> 6, l = t & 63, lr = l & 15, lg = l >> 4;
  const float* base = q + (size_t)b * NC * NHW + qr * 256;
  const float* cwb = cw + qr * 256;

  float4 v[8];
  auto load_chunk = [&](int chunk) {
#pragma unroll
    for (int it = 0; it < 8; ++it) {
      int idx = it * 512 + t;
      int c = idx >> 5, pos = idx & 31;  // 32 float4 per 128-p row
      v[it] = *(const float4*)(base + (size_t)c * NHW + chunk * 128 + pos * 4);
    }
  };
  auto store_chunk = [&](int chunk) {
#pragma unroll
    for (int it = 0; it < 8; ++it) {
      int idx = it * 512 + t;
      int c = idx >> 5, pos = idx & 31;
      float4 vv = v[it];
      float4 wv = *(const float4*)(cwb + chunk * 128 + pos * 4);
      int nl = pos * 4;
      int off = c * 128 + (((nl >> 3) ^ (c & 15)) << 3) + (nl & 7);
      bf16x4v hr, hw;
      hr[0] = (short)f2bf(vv.x); hr[1] = (short)f2bf(vv.y);
      hr[2] = (short)f2bf(vv.z); hr[3] = (short)f2bf(vv.w);
      hw[0] = (short)f2bf(vv.x * wv.x); hw[1] = (short)f2bf(vv.y * wv.y);
      hw[2] = (short)f2bf(vv.z * wv.z); hw[3] = (short)f2bf(vv.w * wv.w);
      *(bf16x4v*)&traw[off] = hr;
      *(bf16x4v*)&twgt[off] = hw;
      float s = vv.x * vv.x + vv.y * vv.y + vv.z * vv.z + vv.w * vv.w;
#pragma unroll
      for (int m = 1; m <= 16; m <<= 1) s += __shfl_xor(s, m, 64);
      if ((l & 31) == 0) ss_loc[c] += s;  // unique writer per (chunk,c)
    }
  };

  load_chunk(0);
  if (t < NC) ss_loc[t] = 0.f;
  __syncthreads();  // ss_loc init visible before any +=
  store_chunk(0);
  __syncthreads();

  f32x4 acc[8];
#pragma unroll
  for (int bt = 0; bt < 8; ++bt) acc[bt] = (f32x4){0.f, 0.f, 0.f, 0.f};

#pragma unroll 1
  for (int chunk = 0; chunk < 2; ++chunk) {
    if (chunk < 1) load_chunk(1);  // issue-early: HBM hides under MFMA
#pragma unroll
    for (int kb = 0; kb < 4; ++kb) {
      int nn = kb * 32 + lg * 8;
      int arow = w * 16 + lr;  // 8 waves x 16 rows = 128 W-rows
      bf16x8 fa = *(const bf16x8*)&twgt[arow * 128 + (((nn >> 3) ^ (arow & 15)) << 3)];
      bf16x8 fb[8];
#pragma unroll
      for (int bt = 0; bt < 8; ++bt) {
        int drow = bt * 16 + lr;
        fb[bt] = *(const bf16x8*)&traw[drow * 128 + (((nn >> 3) ^ (drow & 15)) << 3)];
      }
#pragma unroll
      for (int bt = 0; bt < 8; ++bt)
        acc[bt] = __builtin_amdgcn_mfma_f32_16x16x32_bf16(fa, fb[bt], acc[bt], 0, 0, 0);
    }
    __syncthreads();
    if (chunk < 1) { store_chunk(1); __syncthreads(); }
  }

  if (t < NC) ss[(size_t)(qr * 64 + b) * NC + t] = ss_loc[t];
  float* wb = Wraw + ((size_t)(qr * 64 + b) << 14);
#pragma unroll
  for (int bt = 0; bt < 8; ++bt)
#pragma unroll
    for (int r = 0; r < 4; ++r) {
      int cr = w * 16 + lg * 4 + r;
      int d = bt * 16 + lr;
      wb[cr * NC + d] = acc[bt][r];  // plain store: block owns slab
    }
}

// ---------------- Kernel 4: out[b,j] = <cov_j , rn (x) rn . sum_q Wq_b> ----------------
// grid = 64 (one per b) ; block 512
__global__ __launch_bounds__(512) void k_final(const float* __restrict__ covf,
                                               const float* __restrict__ Wraw,
                                               const float* __restrict__ ss,
                                               float* __restrict__ out) {
  __shared__ float rnl[NC];
  __shared__ float red[8];
  int b = blockIdx.x;
  int t = threadIdx.x;
  int w = t >> 6, l = t & 63;
  if (t < NC) {
    float s = 0.f;
#pragma unroll
    for (int qr = 0; qr < 4; ++qr) s += ss[(size_t)(qr * 64 + b) * NC + t];
    rnl[t] = rsqrtf(s);
  }
  __syncthreads();
  float wm[32];
#pragma unroll
  for (int i = 0; i < 32; ++i) {
    int idx = i * 512 + t;
    float s = 0.f;
#pragma unroll
    for (int qr = 0; qr < 4; ++qr) s += Wraw[((size_t)(qr * 64 + b) << 14) + idx];
    wm[i] = s * rnl[idx >> 7] * rnl[idx & 127];
  }
#pragma unroll 1
  for (int j = 0; j < NWAYS; ++j) {
    const float* cj = covf + ((size_t)j << 14);
    float s = 0.f;
#pragma unroll
    for (int i = 0; i < 32; ++i) s += cj[i * 512 + t] * wm[i];
#pragma unroll
    for (int m = 1; m <= 32; m <<= 1) s += __shfl_xor(s, m, 64);
    if (l == 0) red[w] = s;
    __syncthreads();
    if (t == 0)
      out[b * NWAYS + j] = red[0] + red[1] + red[2] + red[3] +
                           red[4] + red[5] + red[6] + red[7];
    __syncthreads();
  }
}

extern "C" void kernel_launch(void* const* d_in, const int* in_sizes, int n_in,
                              void* d_out, int out_size, void* d_ws, size_t ws_size,
                              hipStream_t stream) {
  (void)in_sizes; (void)n_in; (void)out_size; (void)ws_size;
  const float* q = (const float*)d_in[0];
  const float* sup = (const float*)d_in[1];
  const float* cw = (const float*)d_in[2];
  float* out = (float*)d_out;

  float* Gpart = (float*)d_ws;          // 10*20*16384 f32 = 13.1 MB
  float* mpart = Gpart + 3276800;       // 10*20*128 f32
  float* covf = mpart + 25600;          // 10*16384 f32
  float* Wraw = covf + 163840;          // 4*64*16384 f32 = 16.8 MB
  float* ssb = Wraw + 4194304;          // 4*64*128 f32

  k_covg<<<200, 256, 0, stream>>>(sup, Gpart, mpart);
  k_fin<<<160, 256, 0, stream>>>(Gpart, mpart, covf);
  k_wgram<<<256, 512, 0, stream>>>(q, cw, Wraw, ssb);
  k_final<<<64, 512, 0, stream>>>(covf, Wraw, ssb, out);
}

// Round 5
// 53.319 us; speedup vs baseline: 1.9271x; 1.9271x over previous
//
#include <hip/hip_runtime.h>

typedef unsigned short u16;
typedef unsigned int u32;
typedef __attribute__((ext_vector_type(8))) short bf16x8;
typedef __attribute__((ext_vector_type(4))) short bf16x4v;
typedef __attribute__((ext_vector_type(4))) float f32x4;

#define NWAYS 10
#define NC 128
#define NHW 1024

__device__ __forceinline__ u16 f2bf(float f) {
  u32 u = __builtin_bit_cast(u32, f);
  return (u16)((u + 0x7fffu + ((u >> 16) & 1u)) >> 16);  // RNE
}
__device__ __forceinline__ float bf2f(u16 h) {
  u32 u = ((u32)h) << 16;
  return __builtin_bit_cast(float, u);
}

// ---------------- Kernel 1: per-chunk Gram partials (bf16, no atomics) ----------------
// Gpartb[j*20+chunk][c][d] = bf16(sum_{n in chunk} s_c s_d) ; mpart[j*20+chunk][c] = f32 sum
// grid = 10 classes * 20 chunks of 256 n ; block 256
__global__ __launch_bounds__(256) void k_covg(const float* __restrict__ sup,
                                              u16* __restrict__ Gpartb,
                                              float* __restrict__ mpart) {
  __shared__ u16 tile[NC * 256];  // swizzled [c][n], 64 KiB
  __shared__ float ssum[NC];
  int j = blockIdx.x / 20, chunk = blockIdx.x % 20;
  int shot = chunk >> 2, p0 = (chunk & 3) * 256;
  int t = threadIdx.x;
  const float* srcbase = sup + ((size_t)(j * 5 + shot) * NC) * NHW + p0;
#pragma unroll 8
  for (int it = 0; it < 32; ++it) {
    int c = it * 4 + (t >> 6);
    int pos = t & 63;
    float4 v = *(const float4*)(srcbase + (size_t)c * NHW + pos * 4);
    int nl = pos * 4;
    int idx = c * 256 + (((nl >> 3) ^ (c & 15)) << 3) + (nl & 7);
    bf16x4v h;
    h[0] = (short)f2bf(v.x); h[1] = (short)f2bf(v.y);
    h[2] = (short)f2bf(v.z); h[3] = (short)f2bf(v.w);
    *(bf16x4v*)&tile[idx] = h;
    float s = v.x + v.y + v.z + v.w;
#pragma unroll
    for (int m = 1; m <= 32; m <<= 1) s += __shfl_xor(s, m, 64);
    if ((t & 63) == 0) ssum[c] = s;  // unique writer per row
  }
  __syncthreads();
  if (t < NC) mpart[(size_t)(j * 20 + chunk) * NC + t] = ssum[t];

  int w = t >> 6, l = t & 63, lr = l & 15, lg = l >> 4;
  f32x4 acc[2][8];
#pragma unroll
  for (int a = 0; a < 2; ++a)
#pragma unroll
    for (int bt = 0; bt < 8; ++bt) acc[a][bt] = (f32x4){0.f, 0.f, 0.f, 0.f};
#pragma unroll 1
  for (int kb = 0; kb < 8; ++kb) {
    int nn = kb * 32 + lg * 8;
    bf16x8 frag[8];
#pragma unroll
    for (int ti = 0; ti < 8; ++ti) {
      int cc = ti * 16 + lr;
      frag[ti] = *(const bf16x8*)&tile[cc * 256 + (((nn >> 3) ^ (cc & 15)) << 3)];
    }
    bf16x8 fa[2];
#pragma unroll
    for (int a = 0; a < 2; ++a) {
      int cc = (2 * w + a) * 16 + lr;
      fa[a] = *(const bf16x8*)&tile[cc * 256 + (((nn >> 3) ^ (cc & 15)) << 3)];
    }
#pragma unroll
    for (int a = 0; a < 2; ++a)
#pragma unroll
      for (int bt = 0; bt < 8; ++bt)
        acc[a][bt] = __builtin_amdgcn_mfma_f32_16x16x32_bf16(fa[a], frag[bt], acc[a][bt], 0, 0, 0);
  }
  u16* gp = Gpartb + ((size_t)(j * 20 + chunk) << 14);
#pragma unroll
  for (int a = 0; a < 2; ++a)
#pragma unroll
    for (int bt = 0; bt < 8; ++bt)
#pragma unroll
      for (int r = 0; r < 4; ++r) {
        int cr = (2 * w + a) * 16 + lg * 4 + r;  // C/D: row=(lane>>4)*4+reg
        int d = bt * 16 + lr;                    //      col=lane&15
        gp[cr * NC + d] = f2bf(acc[a][bt][r]);   // plain bf16 store: block owns slab
      }
}

// ---------------- Kernel 2: reduce partials -> bf16 cov ----------------
// grid = 10 j * 16 rowgroups of 8 rows ; block 256 (each thread: 4 consecutive d)
__global__ __launch_bounds__(256) void k_fin(const u16* __restrict__ Gpartb,
                                             const float* __restrict__ mpart,
                                             u16* __restrict__ covb) {
  __shared__ float msd[NC];
  int j = blockIdx.x >> 4, rg = blockIdx.x & 15;
  int t = threadIdx.x;
  if (t < NC) {
    float s = 0.f;
#pragma unroll
    for (int k = 0; k < 20; ++k) s += mpart[(size_t)(j * 20 + k) * NC + t];
    msd[t] = s;
  }
  __syncthreads();
  int e = rg * 1024 + t * 4;  // 8 rows x 128 cols per block
  int c = e >> 7, d0 = e & 127;
  float g[4] = {0.f, 0.f, 0.f, 0.f};
#pragma unroll
  for (int k = 0; k < 20; ++k) {
    bf16x4v v = *(const bf16x4v*)(Gpartb + (((size_t)(j * 20 + k)) << 14) + e);
#pragma unroll
    for (int r = 0; r < 4; ++r) g[r] += bf2f((u16)v[r]);
  }
  bf16x4v o;
#pragma unroll
  for (int r = 0; r < 4; ++r)
    o[r] = (short)f2bf((g[r] - msd[c] * msd[d0 + r] * (1.0f / 5120.0f)) * (1.0f / 5119.0f));
  *(bf16x4v*)(covb + (((size_t)j) << 14) + e) = o;
}

// ---------------- Kernel 3: weighted q-Gram quarters (bf16 out, no atomics) ----------------
// Wrawb[qr*64+b][c][d] = bf16(sum_{p in quarter} w_p q_c q_d) ; ss[qr*64+b][c] = sum q_c^2
// grid = 64 b * 4 quarters of 256 p ; block 512 (8 waves); 2 chunks of 128 p
__global__ __launch_bounds__(512) void k_wgram(const float* __restrict__ q,
                                               const float* __restrict__ cw,
                                               u16* __restrict__ Wrawb,
                                               float* __restrict__ ss) {
  __shared__ u16 traw[NC * 128];  // 32 KiB [c][128p] swizzled
  __shared__ u16 twgt[NC * 128];  // 32 KiB, w_p-scaled
  __shared__ float ss_loc[NC];
  int bid = blockIdx.x;
  int b = bid >> 2, qr = bid & 3;
  int t = threadIdx.x;
  int w = t >> 6, l = t & 63, lr = l & 15, lg = l >> 4;
  const float* base = q + (size_t)b * NC * NHW + qr * 256;
  const float* cwb = cw + qr * 256;

  float4 v[8];
  auto load_chunk = [&](int chunk) {
#pragma unroll
    for (int it = 0; it < 8; ++it) {
      int idx = it * 512 + t;
      int c = idx >> 5, pos = idx & 31;
      v[it] = *(const float4*)(base + (size_t)c * NHW + chunk * 128 + pos * 4);
    }
  };
  auto store_chunk = [&](int chunk) {
#pragma unroll
    for (int it = 0; it < 8; ++it) {
      int idx = it * 512 + t;
      int c = idx >> 5, pos = idx & 31;
      float4 vv = v[it];
      float4 wv = *(const float4*)(cwb + chunk * 128 + pos * 4);
      int nl = pos * 4;
      int off = c * 128 + (((nl >> 3) ^ (c & 15)) << 3) + (nl & 7);
      bf16x4v hr, hw;
      hr[0] = (short)f2bf(vv.x); hr[1] = (short)f2bf(vv.y);
      hr[2] = (short)f2bf(vv.z); hr[3] = (short)f2bf(vv.w);
      hw[0] = (short)f2bf(vv.x * wv.x); hw[1] = (short)f2bf(vv.y * wv.y);
      hw[2] = (short)f2bf(vv.z * wv.z); hw[3] = (short)f2bf(vv.w * wv.w);
      *(bf16x4v*)&traw[off] = hr;
      *(bf16x4v*)&twgt[off] = hw;
      float s = vv.x * vv.x + vv.y * vv.y + vv.z * vv.z + vv.w * vv.w;
#pragma unroll
      for (int m = 1; m <= 16; m <<= 1) s += __shfl_xor(s, m, 64);
      if ((l & 31) == 0) ss_loc[c] += s;  // unique writer per (chunk,c)
    }
  };

  load_chunk(0);
  if (t < NC) ss_loc[t] = 0.f;
  __syncthreads();  // ss_loc init visible before any +=
  store_chunk(0);
  __syncthreads();

  f32x4 acc[8];
#pragma unroll
  for (int bt = 0; bt < 8; ++bt) acc[bt] = (f32x4){0.f, 0.f, 0.f, 0.f};

#pragma unroll 1
  for (int chunk = 0; chunk < 2; ++chunk) {
    if (chunk < 1) load_chunk(1);
#pragma unroll
    for (int kb = 0; kb < 4; ++kb) {
      int nn = kb * 32 + lg * 8;
      int arow = w * 16 + lr;
      bf16x8 fa = *(const bf16x8*)&twgt[arow * 128 + (((nn >> 3) ^ (arow & 15)) << 3)];
      bf16x8 fb[8];
#pragma unroll
      for (int bt = 0; bt < 8; ++bt) {
        int drow = bt * 16 + lr;
        fb[bt] = *(const bf16x8*)&traw[drow * 128 + (((nn >> 3) ^ (drow & 15)) << 3)];
      }
#pragma unroll
      for (int bt = 0; bt < 8; ++bt)
        acc[bt] = __builtin_amdgcn_mfma_f32_16x16x32_bf16(fa, fb[bt], acc[bt], 0, 0, 0);
    }
    __syncthreads();
    if (chunk < 1) { store_chunk(1); __syncthreads(); }
  }

  if (t < NC) ss[(size_t)(qr * 64 + b) * NC + t] = ss_loc[t];
  u16* wb = Wrawb + ((size_t)(qr * 64 + b) << 14);
#pragma unroll
  for (int bt = 0; bt < 8; ++bt)
#pragma unroll
    for (int r = 0; r < 4; ++r) {
      int cr = w * 16 + lg * 4 + r;
      int d = bt * 16 + lr;
      wb[cr * NC + d] = f2bf(acc[bt][r]);
    }
}

// ---------------- Kernel 4: Wn[b][c][d] = bf16( (sum_q Wq) * rn_c * rn_d ) ----------------
// grid = 64 b * 4 rowgroups of 32 rows ; block 256 (each thread: 16 consecutive elems)
__global__ __launch_bounds__(256) void k_wn(const u16* __restrict__ Wrawb,
                                            const float* __restrict__ ss,
                                            u16* __restrict__ Wn) {
  __shared__ float rnl[NC];
  int b = blockIdx.x >> 2, rg = blockIdx.x & 3;
  int t = threadIdx.x;
  if (t < NC) {
    float s = 0.f;
#pragma unroll
    for (int qr = 0; qr < 4; ++qr) s += ss[(size_t)(qr * 64 + b) * NC + t];
    rnl[t] = rsqrtf(s);
  }
  __syncthreads();
  int e = rg * 4096 + t * 16;  // 32 rows x 128 cols per block; 16 elems/thread (c const)
  int c = e >> 7, d0 = e & 127;
  float s16[16];
#pragma unroll
  for (int k = 0; k < 16; ++k) s16[k] = 0.f;
#pragma unroll
  for (int qr = 0; qr < 4; ++qr) {
    bf16x8 v0 = *(const bf16x8*)(Wrawb + (((size_t)(qr * 64 + b)) << 14) + e);
    bf16x8 v1 = *(const bf16x8*)(Wrawb + (((size_t)(qr * 64 + b)) << 14) + e + 8);
#pragma unroll
    for (int k = 0; k < 8; ++k) { s16[k] += bf2f((u16)v0[k]); s16[8 + k] += bf2f((u16)v1[k]); }
  }
  float rc = rnl[c];
  bf16x8 o0, o1;
#pragma unroll
  for (int k = 0; k < 8; ++k) {
    o0[k] = (short)f2bf(s16[k] * rc * rnl[d0 + k]);
    o1[k] = (short)f2bf(s16[8 + k] * rc * rnl[d0 + 8 + k]);
  }
  *(bf16x8*)(Wn + (((size_t)b) << 14) + e) = o0;
  *(bf16x8*)(Wn + (((size_t)b) << 14) + e + 8) = o1;
}

// ---------------- Kernel 5: out[b,j] = <covb_j , Wn_b> ----------------
// grid = 640 (b*10+j) ; block 256 ; 8x bf16x8 pairs per thread
__global__ __launch_bounds__(256) void k_final(const u16* __restrict__ covb,
                                               const u16* __restrict__ Wn,
                                               float* __restrict__ out) {
  __shared__ float red[4];
  int bid = blockIdx.x;
  int b = bid / NWAYS, j = bid - b * NWAYS;
  int t = threadIdx.x;
  const u16* cj = covb + ((size_t)j << 14);
  const u16* wb = Wn + ((size_t)b << 14);
  float s = 0.f;
#pragma unroll
  for (int i = 0; i < 8; ++i) {
    int base = (i * 256 + t) * 8;
    bf16x8 cv = *(const bf16x8*)(cj + base);
    bf16x8 wv = *(const bf16x8*)(wb + base);
#pragma unroll
    for (int k = 0; k < 8; ++k) s += bf2f((u16)cv[k]) * bf2f((u16)wv[k]);
  }
#pragma unroll
  for (int m = 1; m <= 32; m <<= 1) s += __shfl_xor(s, m, 64);
  if ((t & 63) == 0) red[t >> 6] = s;
  __syncthreads();
  if (t == 0) out[bid] = red[0] + red[1] + red[2] + red[3];
}

extern "C" void kernel_launch(void* const* d_in, const int* in_sizes, int n_in,
                              void* d_out, int out_size, void* d_ws, size_t ws_size,
                              hipStream_t stream) {
  (void)in_sizes; (void)n_in; (void)out_size; (void)ws_size;
  const float* q = (const float*)d_in[0];
  const float* sup = (const float*)d_in[1];
  const float* cw = (const float*)d_in[2];
  float* out = (float*)d_out;

  char* p = (char*)d_ws;
  u16* Gpartb = (u16*)p;              p += (size_t)200 * 16384 * 2;  // 6.55 MB
  float* mpart = (float*)p;           p += (size_t)200 * 128 * 4;
  u16* covb = (u16*)p;                p += (size_t)10 * 16384 * 2;
  u16* Wrawb = (u16*)p;               p += (size_t)256 * 16384 * 2;  // 8.4 MB
  float* ssb = (float*)p;             p += (size_t)256 * 128 * 4;
  u16* Wn = (u16*)p;                  /* 64*16384*2 = 2.1 MB */

  k_covg<<<200, 256, 0, stream>>>(sup, Gpartb, mpart);
  k_fin<<<160, 256, 0, stream>>>(Gpartb, mpart, covb);
  k_wgram<<<256, 512, 0, stream>>>(q, cw, Wrawb, ssb);
  k_wn<<<256, 256, 0, stream>>>(Wrawb, ssb, Wn);
  k_final<<<640, 256, 0, stream>>>(covb, Wn, out);
}

// Round 6
// 36.684 us; speedup vs baseline: 2.8010x; 1.4535x over previous
//
#include <hip/hip_runtime.h>

typedef unsigned short u16;
typedef unsigned int u32;
typedef __attribute__((ext_vector_type(8))) short bf16x8;
typedef __attribute__((ext_vector_type(4))) short bf16x4v;
typedef __attribute__((ext_vector_type(4))) float f32x4;

#define NWAYS 10
#define NC 128
#define NHW 1024

__device__ __forceinline__ u16 f2bf(float f) {
  u32 u = __builtin_bit_cast(u32, f);
  return (u16)((u + 0x7fffu + ((u >> 16) & 1u)) >> 16);  // RNE
}
__device__ __forceinline__ float bf2f(u16 h) {
  u32 u = ((u32)h) << 16;
  return __builtin_bit_cast(float, u);
}

// ---------------- Phase 1: fused support-Gram + weighted q-Gram ----------------
// blocks 0..199   : Gpartb[j*20+chunk] = bf16 Gram of 256-n support chunk ; mpart f32 rowsums
// blocks 200..455 : Wrawb[qr*64+b] = bf16 sum_p w_p q_c q_d over 256-p quarter ; ss = sum q_c^2
// block = 512 threads (8 waves); LDS 64.5 KiB -> 2 blocks/CU
__global__ __launch_bounds__(512) void k_phase1(const float* __restrict__ sup,
                                                const float* __restrict__ q,
                                                const float* __restrict__ cw,
                                                u16* __restrict__ Gpartb,
                                                float* __restrict__ mpart,
                                                u16* __restrict__ Wrawb,
                                                float* __restrict__ ss) {
  __shared__ u16 smem[NC * 256];  // 64 KiB
  __shared__ float saux[NC];
  int bid = blockIdx.x;
  int t = threadIdx.x;
  int w = t >> 6, l = t & 63, lr = l & 15, lg = l >> 4;

  if (bid < 200) {
    // ---- covariance Gram over one 256-n chunk ----
    int j = bid / 20, chunk = bid % 20;
    int shot = chunk >> 2, p0 = (chunk & 3) * 256;
    const float* srcbase = sup + ((size_t)(j * 5 + shot) * NC) * NHW + p0;
#pragma unroll 4
    for (int it = 0; it < 16; ++it) {
      int c = it * 8 + w;
      int pos = t & 63;
      float4 v = *(const float4*)(srcbase + (size_t)c * NHW + pos * 4);
      int nl = pos * 4;
      int idx = c * 256 + (((nl >> 3) ^ (c & 15)) << 3) + (nl & 7);
      bf16x4v h;
      h[0] = (short)f2bf(v.x); h[1] = (short)f2bf(v.y);
      h[2] = (short)f2bf(v.z); h[3] = (short)f2bf(v.w);
      *(bf16x4v*)&smem[idx] = h;
      float s = v.x + v.y + v.z + v.w;
#pragma unroll
      for (int m = 1; m <= 32; m <<= 1) s += __shfl_xor(s, m, 64);
      if (l == 0) saux[c] = s;  // wave-uniform c, unique per (it,w)
    }
    __syncthreads();
    if (t < NC) mpart[(size_t)bid * NC + t] = saux[t];

    f32x4 acc[8];
#pragma unroll
    for (int bt = 0; bt < 8; ++bt) acc[bt] = (f32x4){0.f, 0.f, 0.f, 0.f};
#pragma unroll 1
    for (int kb = 0; kb < 8; ++kb) {
      int nn = kb * 32 + lg * 8;
      int arow = w * 16 + lr;  // 8 waves x 16 rows = 128
      bf16x8 fa = *(const bf16x8*)&smem[arow * 256 + (((nn >> 3) ^ (arow & 15)) << 3)];
      bf16x8 fb[8];
#pragma unroll
      for (int bt = 0; bt < 8; ++bt) {
        int drow = bt * 16 + lr;
        fb[bt] = *(const bf16x8*)&smem[drow * 256 + (((nn >> 3) ^ (drow & 15)) << 3)];
      }
#pragma unroll
      for (int bt = 0; bt < 8; ++bt)
        acc[bt] = __builtin_amdgcn_mfma_f32_16x16x32_bf16(fa, fb[bt], acc[bt], 0, 0, 0);
    }
    u16* gp = Gpartb + ((size_t)bid << 14);
#pragma unroll
    for (int bt = 0; bt < 8; ++bt)
#pragma unroll
      for (int r = 0; r < 4; ++r) {
        int cr = w * 16 + lg * 4 + r;  // C/D: row=(lane>>4)*4+reg
        int d = bt * 16 + lr;          //      col=lane&15
        gp[cr * NC + d] = f2bf(acc[bt][r]);
      }
  } else {
    // ---- weighted q-Gram over one 256-p quarter ----
    int bid2 = bid - 200;
    int b = bid2 >> 2, qr = bid2 & 3;
    u16* traw = smem;           // [c][128p] swizzled
    u16* twgt = smem + 16384;   // w_p-scaled
    const float* base = q + (size_t)b * NC * NHW + qr * 256;
    const float* cwb = cw + qr * 256;

    float4 v[8];
    auto load_chunk = [&](int chunk) {
#pragma unroll
      for (int it = 0; it < 8; ++it) {
        int idx = it * 512 + t;
        int c = idx >> 5, pos = idx & 31;
        v[it] = *(const float4*)(base + (size_t)c * NHW + chunk * 128 + pos * 4);
      }
    };
    auto store_chunk = [&](int chunk) {
#pragma unroll
      for (int it = 0; it < 8; ++it) {
        int idx = it * 512 + t;
        int c = idx >> 5, pos = idx & 31;
        float4 vv = v[it];
        float4 wv = *(const float4*)(cwb + chunk * 128 + pos * 4);
        int nl = pos * 4;
        int off = c * 128 + (((nl >> 3) ^ (c & 15)) << 3) + (nl & 7);
        bf16x4v hr, hw;
        hr[0] = (short)f2bf(vv.x); hr[1] = (short)f2bf(vv.y);
        hr[2] = (short)f2bf(vv.z); hr[3] = (short)f2bf(vv.w);
        hw[0] = (short)f2bf(vv.x * wv.x); hw[1] = (short)f2bf(vv.y * wv.y);
        hw[2] = (short)f2bf(vv.z * wv.z); hw[3] = (short)f2bf(vv.w * wv.w);
        *(bf16x4v*)&traw[off] = hr;
        *(bf16x4v*)&twgt[off] = hw;
        float s = vv.x * vv.x + vv.y * vv.y + vv.z * vv.z + vv.w * vv.w;
#pragma unroll
        for (int m = 1; m <= 16; m <<= 1) s += __shfl_xor(s, m, 64);
        if ((l & 31) == 0) saux[c] += s;  // unique writer per (chunk,c)
      }
    };

    load_chunk(0);
    if (t < NC) saux[t] = 0.f;
    __syncthreads();  // init visible before any +=
    store_chunk(0);
    __syncthreads();

    f32x4 acc[8];
#pragma unroll
    for (int bt = 0; bt < 8; ++bt) acc[bt] = (f32x4){0.f, 0.f, 0.f, 0.f};
#pragma unroll 1
    for (int chunk = 0; chunk < 2; ++chunk) {
      if (chunk < 1) load_chunk(1);  // issue-early: HBM hides under MFMA
#pragma unroll
      for (int kb = 0; kb < 4; ++kb) {
        int nn = kb * 32 + lg * 8;
        int arow = w * 16 + lr;
        bf16x8 fa = *(const bf16x8*)&twgt[arow * 128 + (((nn >> 3) ^ (arow & 15)) << 3)];
        bf16x8 fb[8];
#pragma unroll
        for (int bt = 0; bt < 8; ++bt) {
          int drow = bt * 16 + lr;
          fb[bt] = *(const bf16x8*)&traw[drow * 128 + (((nn >> 3) ^ (drow & 15)) << 3)];
        }
#pragma unroll
        for (int bt = 0; bt < 8; ++bt)
          acc[bt] = __builtin_amdgcn_mfma_f32_16x16x32_bf16(fa, fb[bt], acc[bt], 0, 0, 0);
      }
      __syncthreads();
      if (chunk < 1) { store_chunk(1); __syncthreads(); }
    }

    if (t < NC) ss[(size_t)(qr * 64 + b) * NC + t] = saux[t];
    u16* wb = Wrawb + ((size_t)(qr * 64 + b) << 14);
#pragma unroll
    for (int bt = 0; bt < 8; ++bt)
#pragma unroll
      for (int r = 0; r < 4; ++r) {
        int cr = w * 16 + lg * 4 + r;
        int d = bt * 16 + lr;
        wb[cr * NC + d] = f2bf(acc[bt][r]);
      }
  }
}

// ---------------- Phase 2: reduce Gram partials -> bf16 cov ; zero out ----------------
// grid = 10 j * 16 rowgroups of 8 rows ; block 256 (each thread: 4 consecutive d)
__global__ __launch_bounds__(256) void k_fin(const u16* __restrict__ Gpartb,
                                             const float* __restrict__ mpart,
                                             u16* __restrict__ covb,
                                             float* __restrict__ out) {
  __shared__ float msd[NC];
  int j = blockIdx.x >> 4, rg = blockIdx.x & 15;
  int t = threadIdx.x;
  if (blockIdx.x < 3) {
    int o = blockIdx.x * 256 + t;
    if (o < 64 * NWAYS) out[o] = 0.f;
  }
  if (t < NC) {
    float s = 0.f;
#pragma unroll
    for (int k = 0; k < 20; ++k) s += mpart[(size_t)(j * 20 + k) * NC + t];
    msd[t] = s;
  }
  __syncthreads();
  int e = rg * 1024 + t * 4;  // 8 rows x 128 cols per block
  int c = e >> 7, d0 = e & 127;
  float g[4] = {0.f, 0.f, 0.f, 0.f};
#pragma unroll
  for (int k = 0; k < 20; ++k) {
    bf16x4v v = *(const bf16x4v*)(Gpartb + (((size_t)(j * 20 + k)) << 14) + e);
#pragma unroll
    for (int r = 0; r < 4; ++r) g[r] += bf2f((u16)v[r]);
  }
  bf16x4v o;
#pragma unroll
  for (int r = 0; r < 4; ++r)
    o[r] = (short)f2bf((g[r] - msd[c] * msd[d0 + r] * (1.0f / 5120.0f)) * (1.0f / 5119.0f));
  *(bf16x4v*)(covb + (((size_t)j) << 14) + e) = o;
}

// ---------------- Phase 3: Wn chunk in registers, dot with all 10 covs ----------------
// grid = 64 b * 4 rowgroups of 32 rows ; block 256 (16 consecutive elems/thread)
__global__ __launch_bounds__(256) void k_wndot(const u16* __restrict__ Wrawb,
                                               const float* __restrict__ ss,
                                               const u16* __restrict__ covb,
                                               float* __restrict__ out) {
  __shared__ float rnl[NC];
  __shared__ float red[4 * NWAYS];
  int b = blockIdx.x >> 2, rg = blockIdx.x & 3;
  int t = threadIdx.x;
  int w = t >> 6, l = t & 63;
  if (t < NC) {
    float s = 0.f;
#pragma unroll
    for (int qr = 0; qr < 4; ++qr) s += ss[(size_t)(qr * 64 + b) * NC + t];
    rnl[t] = rsqrtf(s);
  }
  __syncthreads();
  int e = rg * 4096 + t * 16;  // 32 rows x 128 cols per block
  int c = e >> 7, d0 = e & 127;
  float wn[16];
#pragma unroll
  for (int k = 0; k < 16; ++k) wn[k] = 0.f;
#pragma unroll
  for (int qr = 0; qr < 4; ++qr) {
    const u16* src = Wrawb + (((size_t)(qr * 64 + b)) << 14) + e;
    bf16x8 v0 = *(const bf16x8*)src;
    bf16x8 v1 = *(const bf16x8*)(src + 8);
#pragma unroll
    for (int k = 0; k < 8; ++k) { wn[k] += bf2f((u16)v0[k]); wn[8 + k] += bf2f((u16)v1[k]); }
  }
  float rc = rnl[c];
#pragma unroll
  for (int k = 0; k < 16; ++k) wn[k] *= rc * rnl[d0 + k];

  float acc[NWAYS];
#pragma unroll
  for (int j = 0; j < NWAYS; ++j) {
    const u16* cj = covb + ((size_t)j << 14) + e;
    bf16x8 c0 = *(const bf16x8*)cj;
    bf16x8 c1 = *(const bf16x8*)(cj + 8);
    float s = 0.f;
#pragma unroll
    for (int k = 0; k < 8; ++k) s += wn[k] * bf2f((u16)c0[k]) + wn[8 + k] * bf2f((u16)c1[k]);
    acc[j] = s;
  }
#pragma unroll
  for (int j = 0; j < NWAYS; ++j)
#pragma unroll
    for (int m = 1; m <= 32; m <<= 1) acc[j] += __shfl_xor(acc[j], m, 64);
  if (l == 0)
#pragma unroll
    for (int j = 0; j < NWAYS; ++j) red[w * NWAYS + j] = acc[j];
  __syncthreads();
  if (t < NWAYS)
    atomicAdd(&out[b * NWAYS + t],
              red[t] + red[NWAYS + t] + red[2 * NWAYS + t] + red[3 * NWAYS + t]);
}

extern "C" void kernel_launch(void* const* d_in, const int* in_sizes, int n_in,
                              void* d_out, int out_size, void* d_ws, size_t ws_size,
                              hipStream_t stream) {
  (void)in_sizes; (void)n_in; (void)out_size; (void)ws_size;
  const float* q = (const float*)d_in[0];
  const float* sup = (const float*)d_in[1];
  const float* cw = (const float*)d_in[2];
  float* out = (float*)d_out;

  char* p = (char*)d_ws;
  u16* Gpartb = (u16*)p;    p += (size_t)200 * 16384 * 2;  // 6.55 MB
  float* mpart = (float*)p; p += (size_t)200 * 128 * 4;
  u16* covb = (u16*)p;      p += (size_t)10 * 16384 * 2;
  u16* Wrawb = (u16*)p;     p += (size_t)256 * 16384 * 2;  // 8.4 MB
  float* ssb = (float*)p;

  k_phase1<<<456, 512, 0, stream>>>(sup, q, cw, Gpartb, mpart, Wrawb, ssb);
  k_fin<<<160, 256, 0, stream>>>(Gpartb, mpart, covb, out);
  k_wndot<<<256, 256, 0, stream>>>(Wrawb, ssb, covb, out);
}